// Round 8
// baseline (6502.000 us; speedup 1.0000x reference)
//
#include <hip/hip_runtime.h>
#include <hip/hip_bf16.h>
#include <math.h>

#define B_    4096
#define V_    9
#define N_    (B_*V_)          // 36864 nodes
#define EK_   (B_*V_*(V_-1))   // 294912 kept edges

typedef unsigned short ushort_t;

__device__ __forceinline__ float b2f(ushort_t u) {
    union { unsigned int i; float f; } x; x.i = ((unsigned int)u) << 16; return x.f;
}
__device__ __forceinline__ ushort_t f2b(float f) {
    union { float f; unsigned int i; } x; x.f = f;
    unsigned int r = x.i + 0x7FFFu + ((x.i >> 16) & 1u);
    return (ushort_t)(r >> 16);
}

// ---------------------------------------------------------------------------
// Batched GEMM for the MLP head: out[M,Nc] = act(A[M,K] @ W[K,Nc] + bias)
// ---------------------------------------------------------------------------
__global__ __launch_bounds__(256) void gemm_act_kernel(
    const float* __restrict__ A, const float* __restrict__ W,
    const float* __restrict__ bias, float* __restrict__ out,
    int K, int Nc, int act)
{
    __shared__ float As[8 * 512];
    const int row0 = blockIdx.x * 8;
    const int tid  = threadIdx.x;

    for (int idx = tid; idx < 8 * K; idx += 256)
        As[idx] = A[row0 * K + idx];
    __syncthreads();

    const int total = 8 * Nc;
    for (int idx = tid; idx < total; idx += 256) {
        int r = idx / Nc;
        int n = idx - r * Nc;
        float acc = bias[n];
        const float* a = &As[r * K];
        for (int k = 0; k < K; ++k)
            acc = fmaf(a[k], W[k * Nc + n], acc);
        if (act == 1) acc = tanhf(acc);
        out[(row0 + r) * Nc + n] = acc;
    }
}

// ---------------------------------------------------------------------------
// One conv layer, compile-time dims -> fully unrolled inner loops.
// Fragments in bf16 LDS with odd-word strides (19, 163) -> conflict-free.
//   qT/kT/vT:  [d][node*4+h]  stride 38 ushorts
//   eT:        [d][le*4+h]    stride 326 ushorts
// ---------------------------------------------------------------------------
template <int XD, int ED2>
__device__ __forceinline__ void conv_layer(
    const float* __restrict__ xs, const float* __restrict__ es,
    const float* __restrict__ wq, const float* __restrict__ wk,
    const float* __restrict__ wv, const float* __restrict__ we,
    const float* __restrict__ weo,
    ushort_t* qT, ushort_t* kT, ushort_t* vT, ushort_t* eT,
    float* en, float* xn, float* la, int tid)
{
    // P1: q,k,v projections (3*9*128) and e projection (81*128)
    for (int idx = tid; idx < 13824; idx += 512) {
        if (idx < 3456) {
            int which = idx / 1152, rem = idx - which * 1152;
            int node = rem >> 7, hd = rem & 127;
            int h = hd >> 5, d = hd & 31;
            const float* w = (which == 0) ? wq : (which == 1) ? wk : wv;
            float acc = 0.f;
            #pragma unroll
            for (int m = 0; m < XD; ++m)
                acc = fmaf(xs[node * XD + m], w[m * 128 + hd], acc);
            ushort_t* dst = (which == 0) ? qT : (which == 1) ? kT : vT;
            dst[d * 38 + node * 4 + h] = f2b(acc);
        } else {
            int r = idx - 3456;
            int le = r >> 7, hd = r & 127;
            int h = hd >> 5, d = hd & 31;
            float acc = 0.f;
            #pragma unroll
            for (int m = 0; m < ED2; ++m)
                acc = fmaf(es[le * ED2 + m], we[m * 128 + hd], acc);
            eT[d * 326 + le * 4 + h] = f2b(acc);
        }
    }
    __syncthreads();

    // P2a: logits[le,h] = (q[dst=j] . (k[src=i]+e)) / sqrt(32)
    for (int idx = tid; idx < 324; idx += 512) {
        int le = idx >> 2, h = idx & 3;
        int i = le / 9, j = le - i * 9;
        float acc = 0.f;
        #pragma unroll
        for (int d = 0; d < 32; ++d)
            acc = fmaf(b2f(qT[d * 38 + j * 4 + h]),
                       b2f(kT[d * 38 + i * 4 + h]) + b2f(eT[d * 326 + le * 4 + h]), acc);
        la[idx] = acc * 0.17677669529663687f;
    }
    __syncthreads();

    // P2b: segment softmax over src i, per (dst j, head h), in place
    for (int s = tid; s < 36; s += 512) {
        int j = s >> 2, h = s & 3;
        float m = -1e30f;
        #pragma unroll
        for (int i = 0; i < 9; ++i) m = fmaxf(m, la[(i * 9 + j) * 4 + h]);
        float ex[9], sum = 0.f;
        #pragma unroll
        for (int i = 0; i < 9; ++i) { ex[i] = __expf(la[(i * 9 + j) * 4 + h] - m); sum += ex[i]; }
        float inv = 1.f / (sum + 1e-16f);
        #pragma unroll
        for (int i = 0; i < 9; ++i) la[(i * 9 + j) * 4 + h] = ex[i] * inv;
    }
    __syncthreads();

    // P3: aggregation -> xn[j,d] = mean_h sum_i alpha * (v[i]+e[le])
    for (int idx = tid; idx < 288; idx += 512) {
        int j = idx >> 5, d = idx & 31;
        float acc = 0.f;
        #pragma unroll
        for (int h = 0; h < 4; ++h)
            #pragma unroll
            for (int i = 0; i < 9; ++i) {
                int le = i * 9 + j;
                acc = fmaf(la[le * 4 + h],
                           b2f(vT[d * 38 + i * 4 + h]) + b2f(eT[d * 326 + le * 4 + h]), acc);
            }
        xn[idx] = acc * 0.25f;
    }
    __syncthreads();   // eT reads done before P4 overwrites (en aliases eT)

    // P4: edge out = concat(x[src], x[dst], e) @ weo -> en
    for (int idx = tid; idx < 2592; idx += 512) {
        int le = idx >> 5, c = idx & 31;
        int i = le / 9, j = le - i * 9;
        float acc = 0.f;
        #pragma unroll
        for (int m = 0; m < XD;  ++m) acc = fmaf(xs[i * XD + m],   weo[m * 32 + c], acc);
        #pragma unroll
        for (int m = 0; m < XD;  ++m) acc = fmaf(xs[j * XD + m],   weo[(XD + m) * 32 + c], acc);
        #pragma unroll
        for (int m = 0; m < ED2; ++m) acc = fmaf(es[le * ED2 + m], weo[(2 * XD + m) * 32 + c], acc);
        en[idx] = acc;
    }
    __syncthreads();   // xs/es reads done before caller overwrites xc/ec
}

// ---------------------------------------------------------------------------
// Fully fused GNN: 3 conv layers + final projections + static index outputs.
// One block (512 threads) per graph.  LDS = 11054 floats = 43.2 KB
// -> 3 blocks/CU (129.6 KB), 24 waves/CU.
// ---------------------------------------------------------------------------
__global__ __launch_bounds__(512, 6) void fused_gnn_kernel(
    const float* __restrict__ nl,    // [B, 117]
    const float* __restrict__ el,    // [B, 405]
    const float* __restrict__ c0_wq, const float* __restrict__ c0_wk,
    const float* __restrict__ c0_wv, const float* __restrict__ c0_we,
    const float* __restrict__ c0_weo,
    const float* __restrict__ c1_wq, const float* __restrict__ c1_wk,
    const float* __restrict__ c1_wv, const float* __restrict__ c1_we,
    const float* __restrict__ c1_weo,
    const float* __restrict__ ln0_g, const float* __restrict__ ln0_b,
    const float* __restrict__ ln1_g, const float* __restrict__ ln1_b,
    const float* __restrict__ w_feat, const float* __restrict__ w_eout,
    float* __restrict__ out)
{
    __shared__ float sm[11054];
    float*    x0s = sm;                      // 117
    float*    e0s = sm + 117;                // 405
    float*    xc  = sm + 522;                // 288
    float*    ec  = sm + 810;                // 2592
    ushort_t* qT  = (ushort_t*)(sm + 3402);  // 1216 us (608 fl)
    ushort_t* kT  = (ushort_t*)(sm + 4010);  // 1216 us
    ushort_t* vT  = (ushort_t*)(sm + 4618);  // 1216 us
    ushort_t* eT  = (ushort_t*)(sm + 5226);  // 10432 us (5216 fl)
    float*    en  = sm + 5226;               // 2592 fl, aliases eT
    float*    xn  = sm + 10442;              // 288
    float*    la  = sm + 10730;              // 324

    const int b   = blockIdx.x;
    const int tid = threadIdx.x;

    // stage layer-0 inputs (symmetrize edge logits on the fly)
    for (int idx = tid; idx < 117; idx += 512) x0s[idx] = nl[b * 117 + idx];
    for (int idx = tid; idx < 405; idx += 512) {
        int le = idx / 5, c = idx - le * 5;
        int i = le / 9, j = le - i * 9;
        e0s[idx] = 0.5f * (el[b * 405 + c * 81 + i * 9 + j] +
                           el[b * 405 + c * 81 + j * 9 + i]);
    }
    __syncthreads();

    for (int layer = 0; layer < 3; ++layer) {
        if (layer == 0)
            conv_layer<13, 5>(x0s, e0s, c0_wq, c0_wk, c0_wv, c0_we, c0_weo,
                              qT, kT, vT, eT, en, xn, la, tid);
        else
            conv_layer<32, 32>(xc, ec, c1_wq, c1_wk, c1_wv, c1_we, c1_weo,
                               qT, kT, vT, eT, en, xn, la, tid);

        // P5 (layers 0,1 only): x = leaky(LN(xn)), e = leaky(en)
        if (layer < 2) {
            const float* g  = (layer == 0) ? ln0_g : ln1_g;
            const float* be = (layer == 0) ? ln0_b : ln1_b;
            for (int idx = tid; idx < 288; idx += 512) {
                int j = idx >> 5, c = idx & 31;
                float mu = 0.f;
                #pragma unroll
                for (int t = 0; t < 32; ++t) mu += xn[j * 32 + t];
                mu *= (1.f / 32.f);
                float var = 0.f;
                #pragma unroll
                for (int t = 0; t < 32; ++t) { float d = xn[j * 32 + t] - mu; var = fmaf(d, d, var); }
                var *= (1.f / 32.f);
                float val = (xn[idx] - mu) / sqrtf(var + 1e-5f);
                val = val * g[c] + be[c];
                xc[idx] = (val > 0.f) ? val : 0.01f * val;
            }
            for (int idx = tid; idx < 2592; idx += 512) {
                float v = en[idx];
                ec[idx] = (v > 0.f) ? v : 0.01f * v;
            }
            __syncthreads();
        }
    }

    // Finals.  After layer 2 (no post): xn [9,32] raw, en [81,32] raw.
    float* out_x  = out;                       // [36864,10]
    float* out_e  = out + 368640;              // [294912,5]
    float* out_ei = out + 1843200;             // [2,294912]
    float* out_b  = out + 2433024;             // [36864]

    for (int idx = tid; idx < 90; idx += 512) {         // x @ w_feat
        int j = idx / 10, c = idx - j * 10;
        float acc = 0.f;
        #pragma unroll
        for (int kk = 0; kk < 32; ++kk) acc = fmaf(xn[j * 32 + kk], w_feat[kk * 10 + c], acc);
        out_x[(b * 9 + j) * 10 + c] = acc;
    }
    for (int idx = tid; idx < 360; idx += 512) {        // masked eattr @ w_eout
        int r = idx / 5, c = idx - r * 5;
        int i = r >> 3, jj = r & 7;
        int j = jj + (jj >= i ? 1 : 0);
        const float* row = &en[(i * 9 + j) * 32];
        float acc = 0.f;
        #pragma unroll
        for (int kk = 0; kk < 32; ++kk) acc = fmaf(row[kk], w_eout[kk * 5 + c], acc);
        out_e[(b * 72 + r) * 5 + c] = acc;
    }
    for (int idx = tid; idx < 72; idx += 512) {         // edge_index
        int i = idx >> 3, jj = idx & 7;
        int j = jj + (jj >= i ? 1 : 0);
        out_ei[b * 72 + idx]          = (float)(b * 9 + i);
        out_ei[294912 + b * 72 + idx] = (float)(b * 9 + j);
    }
    for (int idx = tid; idx < 9; idx += 512)            // batch
        out_b[b * 9 + idx] = (float)b;
}

// ---------------------------------------------------------------------------
extern "C" void kernel_launch(void* const* d_in, const int* in_sizes, int n_in,
                              void* d_out, int out_size, void* d_ws, size_t ws_size,
                              hipStream_t stream)
{
    const float* latent  = (const float*)d_in[0];
    const float* w_mlp0  = (const float*)d_in[1];
    const float* b_mlp0  = (const float*)d_in[2];
    const float* w_mlp1  = (const float*)d_in[3];
    const float* b_mlp1  = (const float*)d_in[4];
    const float* w_mlp2  = (const float*)d_in[5];
    const float* b_mlp2  = (const float*)d_in[6];
    const float* w_edges = (const float*)d_in[7];
    const float* b_edges = (const float*)d_in[8];
    const float* w_nodes = (const float*)d_in[9];
    const float* b_nodes = (const float*)d_in[10];
    const float* c0_wq   = (const float*)d_in[11];
    const float* c0_wk   = (const float*)d_in[12];
    const float* c0_wv   = (const float*)d_in[13];
    const float* c0_we   = (const float*)d_in[14];
    const float* c0_weo  = (const float*)d_in[15];
    const float* c1_wq   = (const float*)d_in[16];
    const float* c1_wk   = (const float*)d_in[17];
    const float* c1_wv   = (const float*)d_in[18];
    const float* c1_we   = (const float*)d_in[19];
    const float* c1_weo  = (const float*)d_in[20];
    const float* ln0_g   = (const float*)d_in[21];
    const float* ln0_b   = (const float*)d_in[22];
    const float* ln1_g   = (const float*)d_in[23];
    const float* ln1_b   = (const float*)d_in[24];
    const float* w_feat  = (const float*)d_in[25];
    const float* w_eout  = (const float*)d_in[26];

    // Workspace layout with lifetime overlap (peak 18.3 MB)
    float* ws = (float*)d_ws;
    float* h0 = ws;
    float* el = ws;
    float* h1 = ws + 1658880;
    float* nl = ws + 1658880;
    float* h2 = ws + 2707456;

    float* out = (float*)d_out;

    gemm_act_kernel<<<512, 256, 0, stream>>>(latent, w_mlp0, b_mlp0, h0, 128, 128, 1);
    gemm_act_kernel<<<512, 256, 0, stream>>>(h0, w_mlp1, b_mlp1, h1, 128, 256, 1);
    gemm_act_kernel<<<512, 256, 0, stream>>>(h1, w_mlp2, b_mlp2, h2, 256, 512, 1);
    gemm_act_kernel<<<512, 256, 0, stream>>>(h2, w_edges, b_edges, el, 512, 405, 0);
    gemm_act_kernel<<<512, 256, 0, stream>>>(h2, w_nodes, b_nodes, nl, 512, 117, 0);

    fused_gnn_kernel<<<B_, 512, 0, stream>>>(nl, el,
        c0_wq, c0_wk, c0_wv, c0_we, c0_weo,
        c1_wq, c1_wk, c1_wv, c1_we, c1_weo,
        ln0_g, ln0_b, ln1_g, ln1_b, w_feat, w_eout, out);
}

// Round 10
// 4279.729 us; speedup vs baseline: 1.5193x; 1.5193x over previous
//
#include <hip/hip_runtime.h>
#include <hip/hip_bf16.h>
#include <math.h>

#define B_    4096
#define V_    9
#define N_    (B_*V_)          // 36864 nodes
#define EK_   (B_*V_*(V_-1))   // 294912 kept edges

typedef unsigned short ushort_t;

__device__ __forceinline__ float b2f(ushort_t u) {
    union { unsigned int i; float f; } x; x.i = ((unsigned int)u) << 16; return x.f;
}
__device__ __forceinline__ ushort_t f2b(float f) {
    union { float f; unsigned int i; } x; x.f = f;
    unsigned int r = x.i + 0x7FFFu + ((x.i >> 16) & 1u);
    return (ushort_t)(r >> 16);
}

// ---------------------------------------------------------------------------
// Batched GEMM for the MLP head: out[M,Nc] = act(A[M,K] @ W[K,Nc] + bias)
// ---------------------------------------------------------------------------
__global__ __launch_bounds__(256) void gemm_act_kernel(
    const float* __restrict__ A, const float* __restrict__ W,
    const float* __restrict__ bias, float* __restrict__ out,
    int K, int Nc, int act)
{
    __shared__ float As[8 * 512];
    const int row0 = blockIdx.x * 8;
    const int tid  = threadIdx.x;

    for (int idx = tid; idx < 8 * K; idx += 256)
        As[idx] = A[row0 * K + idx];
    __syncthreads();

    const int total = 8 * Nc;
    for (int idx = tid; idx < total; idx += 256) {
        int r = idx / Nc;
        int n = idx - r * Nc;
        float acc = bias[n];
        const float* a = &As[r * K];
        for (int k = 0; k < K; ++k)
            acc = fmaf(a[k], W[k * Nc + n], acc);
        if (act == 1) acc = tanhf(acc);
        out[(row0 + r) * Nc + n] = acc;
    }
}

// ---------------------------------------------------------------------------
// One conv layer, compile-time dims -> fully unrolled inner loops.
// Fragments in bf16 LDS with odd-word strides (19, 163) -> conflict-free.
//   qT/kT/vT:  [d][node*4+h]  stride 38 ushorts
//   eT:        [d][le*4+h]    stride 326 ushorts
// ---------------------------------------------------------------------------
template <int XD, int ED2>
__device__ __forceinline__ void conv_layer(
    const float* __restrict__ xs, const float* __restrict__ es,
    const float* __restrict__ wq, const float* __restrict__ wk,
    const float* __restrict__ wv, const float* __restrict__ we,
    const float* __restrict__ weo,
    ushort_t* qT, ushort_t* kT, ushort_t* vT, ushort_t* eT,
    float* en, float* xn, float* la, int tid)
{
    // P1: q,k,v projections (3*9*128) and e projection (81*128)
    for (int idx = tid; idx < 13824; idx += 512) {
        if (idx < 3456) {
            int which = idx / 1152, rem = idx - which * 1152;
            int node = rem >> 7, hd = rem & 127;
            int h = hd >> 5, d = hd & 31;
            const float* w = (which == 0) ? wq : (which == 1) ? wk : wv;
            float acc = 0.f;
            #pragma unroll
            for (int m = 0; m < XD; ++m)
                acc = fmaf(xs[node * XD + m], w[m * 128 + hd], acc);
            ushort_t* dst = (which == 0) ? qT : (which == 1) ? kT : vT;
            dst[d * 38 + node * 4 + h] = f2b(acc);
        } else {
            int r = idx - 3456;
            int le = r >> 7, hd = r & 127;
            int h = hd >> 5, d = hd & 31;
            float acc = 0.f;
            #pragma unroll
            for (int m = 0; m < ED2; ++m)
                acc = fmaf(es[le * ED2 + m], we[m * 128 + hd], acc);
            eT[d * 326 + le * 4 + h] = f2b(acc);
        }
    }
    __syncthreads();

    // P2a: logits[le,h] = (q[dst=j] . (k[src=i]+e)) / sqrt(32)
    for (int idx = tid; idx < 324; idx += 512) {
        int le = idx >> 2, h = idx & 3;
        int i = le / 9, j = le - i * 9;
        float acc = 0.f;
        #pragma unroll
        for (int d = 0; d < 32; ++d)
            acc = fmaf(b2f(qT[d * 38 + j * 4 + h]),
                       b2f(kT[d * 38 + i * 4 + h]) + b2f(eT[d * 326 + le * 4 + h]), acc);
        la[idx] = acc * 0.17677669529663687f;
    }
    __syncthreads();

    // P2b: segment softmax over src i, per (dst j, head h), in place
    for (int s = tid; s < 36; s += 512) {
        int j = s >> 2, h = s & 3;
        float m = -1e30f;
        #pragma unroll
        for (int i = 0; i < 9; ++i) m = fmaxf(m, la[(i * 9 + j) * 4 + h]);
        float ex[9], sum = 0.f;
        #pragma unroll
        for (int i = 0; i < 9; ++i) { ex[i] = __expf(la[(i * 9 + j) * 4 + h] - m); sum += ex[i]; }
        float inv = 1.f / (sum + 1e-16f);
        #pragma unroll
        for (int i = 0; i < 9; ++i) la[(i * 9 + j) * 4 + h] = ex[i] * inv;
    }
    __syncthreads();

    // P3: aggregation -> xn[j,d] = mean_h sum_i alpha * (v[i]+e[le])
    for (int idx = tid; idx < 288; idx += 512) {
        int j = idx >> 5, d = idx & 31;
        float acc = 0.f;
        #pragma unroll
        for (int h = 0; h < 4; ++h)
            #pragma unroll
            for (int i = 0; i < 9; ++i) {
                int le = i * 9 + j;
                acc = fmaf(la[le * 4 + h],
                           b2f(vT[d * 38 + i * 4 + h]) + b2f(eT[d * 326 + le * 4 + h]), acc);
            }
        xn[idx] = acc * 0.25f;
    }
    __syncthreads();   // eT reads done before P4 overwrites (en aliases eT)

    // P4: edge out = concat(x[src], x[dst], e) @ weo -> en
    for (int idx = tid; idx < 2592; idx += 512) {
        int le = idx >> 5, c = idx & 31;
        int i = le / 9, j = le - i * 9;
        float acc = 0.f;
        #pragma unroll
        for (int m = 0; m < XD;  ++m) acc = fmaf(xs[i * XD + m],   weo[m * 32 + c], acc);
        #pragma unroll
        for (int m = 0; m < XD;  ++m) acc = fmaf(xs[j * XD + m],   weo[(XD + m) * 32 + c], acc);
        #pragma unroll
        for (int m = 0; m < ED2; ++m) acc = fmaf(es[le * ED2 + m], weo[(2 * XD + m) * 32 + c], acc);
        en[idx] = acc;
    }
    __syncthreads();   // xs/es reads done before caller overwrites xc/ec
}

// ---------------------------------------------------------------------------
// Fully fused GNN: 3 conv layers + final projections + static index outputs.
// One block (512 threads) per graph.  LDS = 11054 floats = 43.2 KB.
// __launch_bounds__(512, 4): VGPR cap 64 -> 2 blocks/CU (16 waves), NO SPILLS.
// (512,6) capped VGPR at 40 and spilled 14 GB/dispatch to scratch -- measured
// round 8: FETCH 10.7 GB, VALUBusy 5.8%. Spills cost more than occupancy.
// ---------------------------------------------------------------------------
__global__ __launch_bounds__(512, 4) void fused_gnn_kernel(
    const float* __restrict__ nl,    // [B, 117]
    const float* __restrict__ el,    // [B, 405]
    const float* __restrict__ c0_wq, const float* __restrict__ c0_wk,
    const float* __restrict__ c0_wv, const float* __restrict__ c0_we,
    const float* __restrict__ c0_weo,
    const float* __restrict__ c1_wq, const float* __restrict__ c1_wk,
    const float* __restrict__ c1_wv, const float* __restrict__ c1_we,
    const float* __restrict__ c1_weo,
    const float* __restrict__ ln0_g, const float* __restrict__ ln0_b,
    const float* __restrict__ ln1_g, const float* __restrict__ ln1_b,
    const float* __restrict__ w_feat, const float* __restrict__ w_eout,
    float* __restrict__ out)
{
    __shared__ float sm[11054];
    float*    x0s = sm;                      // 117
    float*    e0s = sm + 117;                // 405
    float*    xc  = sm + 522;                // 288
    float*    ec  = sm + 810;                // 2592
    ushort_t* qT  = (ushort_t*)(sm + 3402);  // 1216 us (608 fl)
    ushort_t* kT  = (ushort_t*)(sm + 4010);  // 1216 us
    ushort_t* vT  = (ushort_t*)(sm + 4618);  // 1216 us
    ushort_t* eT  = (ushort_t*)(sm + 5226);  // 10432 us (5216 fl)
    float*    en  = sm + 5226;               // 2592 fl, aliases eT
    float*    xn  = sm + 10442;              // 288
    float*    la  = sm + 10730;              // 324

    const int b   = blockIdx.x;
    const int tid = threadIdx.x;

    // stage layer-0 inputs (symmetrize edge logits on the fly)
    for (int idx = tid; idx < 117; idx += 512) x0s[idx] = nl[b * 117 + idx];
    for (int idx = tid; idx < 405; idx += 512) {
        int le = idx / 5, c = idx - le * 5;
        int i = le / 9, j = le - i * 9;
        e0s[idx] = 0.5f * (el[b * 405 + c * 81 + i * 9 + j] +
                           el[b * 405 + c * 81 + j * 9 + i]);
    }
    __syncthreads();

    for (int layer = 0; layer < 3; ++layer) {
        if (layer == 0)
            conv_layer<13, 5>(x0s, e0s, c0_wq, c0_wk, c0_wv, c0_we, c0_weo,
                              qT, kT, vT, eT, en, xn, la, tid);
        else
            conv_layer<32, 32>(xc, ec, c1_wq, c1_wk, c1_wv, c1_we, c1_weo,
                               qT, kT, vT, eT, en, xn, la, tid);

        // P5 (layers 0,1 only): x = leaky(LN(xn)), e = leaky(en)
        if (layer < 2) {
            const float* g  = (layer == 0) ? ln0_g : ln1_g;
            const float* be = (layer == 0) ? ln0_b : ln1_b;
            for (int idx = tid; idx < 288; idx += 512) {
                int j = idx >> 5, c = idx & 31;
                float mu = 0.f;
                #pragma unroll
                for (int t = 0; t < 32; ++t) mu += xn[j * 32 + t];
                mu *= (1.f / 32.f);
                float var = 0.f;
                #pragma unroll
                for (int t = 0; t < 32; ++t) { float d = xn[j * 32 + t] - mu; var = fmaf(d, d, var); }
                var *= (1.f / 32.f);
                float val = (xn[idx] - mu) / sqrtf(var + 1e-5f);
                val = val * g[c] + be[c];
                xc[idx] = (val > 0.f) ? val : 0.01f * val;
            }
            for (int idx = tid; idx < 2592; idx += 512) {
                float v = en[idx];
                ec[idx] = (v > 0.f) ? v : 0.01f * v;
            }
            __syncthreads();
        }
    }

    // Finals.  After layer 2 (no post): xn [9,32] raw, en [81,32] raw.
    float* out_x  = out;                       // [36864,10]
    float* out_e  = out + 368640;              // [294912,5]
    float* out_ei = out + 1843200;             // [2,294912]
    float* out_b  = out + 2433024;             // [36864]

    for (int idx = tid; idx < 90; idx += 512) {         // x @ w_feat
        int j = idx / 10, c = idx - j * 10;
        float acc = 0.f;
        #pragma unroll
        for (int kk = 0; kk < 32; ++kk) acc = fmaf(xn[j * 32 + kk], w_feat[kk * 10 + c], acc);
        out_x[(b * 9 + j) * 10 + c] = acc;
    }
    for (int idx = tid; idx < 360; idx += 512) {        // masked eattr @ w_eout
        int r = idx / 5, c = idx - r * 5;
        int i = r >> 3, jj = r & 7;
        int j = jj + (jj >= i ? 1 : 0);
        const float* row = &en[(i * 9 + j) * 32];
        float acc = 0.f;
        #pragma unroll
        for (int kk = 0; kk < 32; ++kk) acc = fmaf(row[kk], w_eout[kk * 5 + c], acc);
        out_e[(b * 72 + r) * 5 + c] = acc;
    }
    for (int idx = tid; idx < 72; idx += 512) {         // edge_index
        int i = idx >> 3, jj = idx & 7;
        int j = jj + (jj >= i ? 1 : 0);
        out_ei[b * 72 + idx]          = (float)(b * 9 + i);
        out_ei[294912 + b * 72 + idx] = (float)(b * 9 + j);
    }
    for (int idx = tid; idx < 9; idx += 512)            // batch
        out_b[b * 9 + idx] = (float)b;
}

// ---------------------------------------------------------------------------
extern "C" void kernel_launch(void* const* d_in, const int* in_sizes, int n_in,
                              void* d_out, int out_size, void* d_ws, size_t ws_size,
                              hipStream_t stream)
{
    const float* latent  = (const float*)d_in[0];
    const float* w_mlp0  = (const float*)d_in[1];
    const float* b_mlp0  = (const float*)d_in[2];
    const float* w_mlp1  = (const float*)d_in[3];
    const float* b_mlp1  = (const float*)d_in[4];
    const float* w_mlp2  = (const float*)d_in[5];
    const float* b_mlp2  = (const float*)d_in[6];
    const float* w_edges = (const float*)d_in[7];
    const float* b_edges = (const float*)d_in[8];
    const float* w_nodes = (const float*)d_in[9];
    const float* b_nodes = (const float*)d_in[10];
    const float* c0_wq   = (const float*)d_in[11];
    const float* c0_wk   = (const float*)d_in[12];
    const float* c0_wv   = (const float*)d_in[13];
    const float* c0_we   = (const float*)d_in[14];
    const float* c0_weo  = (const float*)d_in[15];
    const float* c1_wq   = (const float*)d_in[16];
    const float* c1_wk   = (const float*)d_in[17];
    const float* c1_wv   = (const float*)d_in[18];
    const float* c1_we   = (const float*)d_in[19];
    const float* c1_weo  = (const float*)d_in[20];
    const float* ln0_g   = (const float*)d_in[21];
    const float* ln0_b   = (const float*)d_in[22];
    const float* ln1_g   = (const float*)d_in[23];
    const float* ln1_b   = (const float*)d_in[24];
    const float* w_feat  = (const float*)d_in[25];
    const float* w_eout  = (const float*)d_in[26];

    // Workspace layout with lifetime overlap (peak 18.3 MB)
    float* ws = (float*)d_ws;
    float* h0 = ws;
    float* el = ws;
    float* h1 = ws + 1658880;
    float* nl = ws + 1658880;
    float* h2 = ws + 2707456;

    float* out = (float*)d_out;

    gemm_act_kernel<<<512, 256, 0, stream>>>(latent, w_mlp0, b_mlp0, h0, 128, 128, 1);
    gemm_act_kernel<<<512, 256, 0, stream>>>(h0, w_mlp1, b_mlp1, h1, 128, 256, 1);
    gemm_act_kernel<<<512, 256, 0, stream>>>(h1, w_mlp2, b_mlp2, h2, 256, 512, 1);
    gemm_act_kernel<<<512, 256, 0, stream>>>(h2, w_edges, b_edges, el, 512, 405, 0);
    gemm_act_kernel<<<512, 256, 0, stream>>>(h2, w_nodes, b_nodes, nl, 512, 117, 0);

    fused_gnn_kernel<<<B_, 512, 0, stream>>>(nl, el,
        c0_wq, c0_wk, c0_wv, c0_we, c0_weo,
        c1_wq, c1_wk, c1_wv, c1_we, c1_weo,
        ln0_g, ln0_b, ln1_g, ln1_b, w_feat, w_eout, out);
}

// Round 11
// 3128.924 us; speedup vs baseline: 2.0780x; 1.3678x over previous
//
#include <hip/hip_runtime.h>
#include <hip/hip_bf16.h>
#include <math.h>

#define B_    4096
#define V_    9
#define N_    (B_*V_)          // 36864 nodes
#define EK_   (B_*V_*(V_-1))   // 294912 kept edges

typedef unsigned short ushort_t;

__device__ __forceinline__ float b2f(ushort_t u) {
    union { unsigned int i; float f; } x; x.i = ((unsigned int)u) << 16; return x.f;
}
__device__ __forceinline__ ushort_t f2b(float f) {
    union { float f; unsigned int i; } x; x.f = f;
    unsigned int r = x.i + 0x7FFFu + ((x.i >> 16) & 1u);
    return (ushort_t)(r >> 16);
}

// ---------------------------------------------------------------------------
// Batched GEMM for the MLP head: out[M,Nc] = act(A[M,K] @ W[K,Nc] + bias)
// ---------------------------------------------------------------------------
__global__ __launch_bounds__(256) void gemm_act_kernel(
    const float* __restrict__ A, const float* __restrict__ W,
    const float* __restrict__ bias, float* __restrict__ out,
    int K, int Nc, int act)
{
    __shared__ float As[8 * 512];
    const int row0 = blockIdx.x * 8;
    const int tid  = threadIdx.x;

    for (int idx = tid; idx < 8 * K; idx += 256)
        As[idx] = A[row0 * K + idx];
    __syncthreads();

    const int total = 8 * Nc;
    for (int idx = tid; idx < total; idx += 256) {
        int r = idx / Nc;
        int n = idx - r * Nc;
        float acc = bias[n];
        const float* a = &As[r * K];
        for (int k = 0; k < K; ++k)
            acc = fmaf(a[k], W[k * Nc + n], acc);
        if (act == 1) acc = tanhf(acc);
        out[(row0 + r) * Nc + n] = acc;
    }
}

// ---------------------------------------------------------------------------
// One conv layer, compile-time dims -> fully unrolled inner loops.
// Fragments in bf16 LDS with odd-word strides (19, 163) -> conflict-free.
//   qT/kT/vT:  [d][node*4+h]  stride 38 ushorts
//   eT:        [d][le*4+h]    stride 326 ushorts
// ---------------------------------------------------------------------------
template <int XD, int ED2>
__device__ __forceinline__ void conv_layer(
    const float* __restrict__ xs, const float* __restrict__ es,
    const float* __restrict__ wq, const float* __restrict__ wk,
    const float* __restrict__ wv, const float* __restrict__ we,
    const float* __restrict__ weo,
    ushort_t* qT, ushort_t* kT, ushort_t* vT, ushort_t* eT,
    float* en, float* xn, float* la, int tid)
{
    // P1: q,k,v projections (3*9*128) and e projection (81*128)
    for (int idx = tid; idx < 13824; idx += 512) {
        if (idx < 3456) {
            int which = idx / 1152, rem = idx - which * 1152;
            int node = rem >> 7, hd = rem & 127;
            int h = hd >> 5, d = hd & 31;
            const float* w = (which == 0) ? wq : (which == 1) ? wk : wv;
            float acc = 0.f;
            #pragma unroll
            for (int m = 0; m < XD; ++m)
                acc = fmaf(xs[node * XD + m], w[m * 128 + hd], acc);
            ushort_t* dst = (which == 0) ? qT : (which == 1) ? kT : vT;
            dst[d * 38 + node * 4 + h] = f2b(acc);
        } else {
            int r = idx - 3456;
            int le = r >> 7, hd = r & 127;
            int h = hd >> 5, d = hd & 31;
            float acc = 0.f;
            #pragma unroll
            for (int m = 0; m < ED2; ++m)
                acc = fmaf(es[le * ED2 + m], we[m * 128 + hd], acc);
            eT[d * 326 + le * 4 + h] = f2b(acc);
        }
    }
    __syncthreads();

    // P2a: logits[le,h] = (q[dst=j] . (k[src=i]+e)) / sqrt(32)
    for (int idx = tid; idx < 324; idx += 512) {
        int le = idx >> 2, h = idx & 3;
        int i = le / 9, j = le - i * 9;
        float acc = 0.f;
        #pragma unroll
        for (int d = 0; d < 32; ++d)
            acc = fmaf(b2f(qT[d * 38 + j * 4 + h]),
                       b2f(kT[d * 38 + i * 4 + h]) + b2f(eT[d * 326 + le * 4 + h]), acc);
        la[idx] = acc * 0.17677669529663687f;
    }
    __syncthreads();

    // P2b: segment softmax over src i, per (dst j, head h), in place
    for (int s = tid; s < 36; s += 512) {
        int j = s >> 2, h = s & 3;
        float m = -1e30f;
        #pragma unroll
        for (int i = 0; i < 9; ++i) m = fmaxf(m, la[(i * 9 + j) * 4 + h]);
        float ex[9], sum = 0.f;
        #pragma unroll
        for (int i = 0; i < 9; ++i) { ex[i] = __expf(la[(i * 9 + j) * 4 + h] - m); sum += ex[i]; }
        float inv = 1.f / (sum + 1e-16f);
        #pragma unroll
        for (int i = 0; i < 9; ++i) la[(i * 9 + j) * 4 + h] = ex[i] * inv;
    }
    __syncthreads();

    // P3: aggregation -> xn[j,d] = mean_h sum_i alpha * (v[i]+e[le])
    for (int idx = tid; idx < 288; idx += 512) {
        int j = idx >> 5, d = idx & 31;
        float acc = 0.f;
        #pragma unroll
        for (int h = 0; h < 4; ++h)
            #pragma unroll
            for (int i = 0; i < 9; ++i) {
                int le = i * 9 + j;
                acc = fmaf(la[le * 4 + h],
                           b2f(vT[d * 38 + i * 4 + h]) + b2f(eT[d * 326 + le * 4 + h]), acc);
            }
        xn[idx] = acc * 0.25f;
    }
    __syncthreads();   // eT reads done before P4 overwrites (en aliases eT)

    // P4: edge out = concat(x[src], x[dst], e) @ weo -> en
    for (int idx = tid; idx < 2592; idx += 512) {
        int le = idx >> 5, c = idx & 31;
        int i = le / 9, j = le - i * 9;
        float acc = 0.f;
        #pragma unroll
        for (int m = 0; m < XD;  ++m) acc = fmaf(xs[i * XD + m],   weo[m * 32 + c], acc);
        #pragma unroll
        for (int m = 0; m < XD;  ++m) acc = fmaf(xs[j * XD + m],   weo[(XD + m) * 32 + c], acc);
        #pragma unroll
        for (int m = 0; m < ED2; ++m) acc = fmaf(es[le * ED2 + m], weo[(2 * XD + m) * 32 + c], acc);
        en[idx] = acc;
    }
    __syncthreads();   // xs/es reads done before caller overwrites xc/ec
}

// ---------------------------------------------------------------------------
// Fully fused GNN: 3 conv layers + final projections + static index outputs.
// One block (512 threads) per graph.  LDS = 11054 floats = 43.2 KB.
// __launch_bounds__(512, 2): VGPR cap 128.  Measured spill ladder:
//   cap 40 (512,6): 14 GB scratch/dispatch, 6.1 ms   (round 8)
//   cap 64 (512,4): 3.9 GB scratch/dispatch, 3.9 ms  (round 10)
//   natural 76, no cap, but 72KB LDS -> 1 block/CU: 3.8 ms (round 7)
// cap 128 + 43.5KB LDS -> no spills AND 2 blocks/CU (16 waves).
// ---------------------------------------------------------------------------
__global__ __launch_bounds__(512, 2) void fused_gnn_kernel(
    const float* __restrict__ nl,    // [B, 117]
    const float* __restrict__ el,    // [B, 405]
    const float* __restrict__ c0_wq, const float* __restrict__ c0_wk,
    const float* __restrict__ c0_wv, const float* __restrict__ c0_we,
    const float* __restrict__ c0_weo,
    const float* __restrict__ c1_wq, const float* __restrict__ c1_wk,
    const float* __restrict__ c1_wv, const float* __restrict__ c1_we,
    const float* __restrict__ c1_weo,
    const float* __restrict__ ln0_g, const float* __restrict__ ln0_b,
    const float* __restrict__ ln1_g, const float* __restrict__ ln1_b,
    const float* __restrict__ w_feat, const float* __restrict__ w_eout,
    float* __restrict__ out)
{
    __shared__ float sm[11054];
    float*    x0s = sm;                      // 117
    float*    e0s = sm + 117;                // 405
    float*    xc  = sm + 522;                // 288
    float*    ec  = sm + 810;                // 2592
    ushort_t* qT  = (ushort_t*)(sm + 3402);  // 1216 us (608 fl)
    ushort_t* kT  = (ushort_t*)(sm + 4010);  // 1216 us
    ushort_t* vT  = (ushort_t*)(sm + 4618);  // 1216 us
    ushort_t* eT  = (ushort_t*)(sm + 5226);  // 10432 us (5216 fl)
    float*    en  = sm + 5226;               // 2592 fl, aliases eT
    float*    xn  = sm + 10442;              // 288
    float*    la  = sm + 10730;              // 324

    const int b   = blockIdx.x;
    const int tid = threadIdx.x;

    // stage layer-0 inputs (symmetrize edge logits on the fly)
    for (int idx = tid; idx < 117; idx += 512) x0s[idx] = nl[b * 117 + idx];
    for (int idx = tid; idx < 405; idx += 512) {
        int le = idx / 5, c = idx - le * 5;
        int i = le / 9, j = le - i * 9;
        e0s[idx] = 0.5f * (el[b * 405 + c * 81 + i * 9 + j] +
                           el[b * 405 + c * 81 + j * 9 + i]);
    }
    __syncthreads();

    for (int layer = 0; layer < 3; ++layer) {
        if (layer == 0)
            conv_layer<13, 5>(x0s, e0s, c0_wq, c0_wk, c0_wv, c0_we, c0_weo,
                              qT, kT, vT, eT, en, xn, la, tid);
        else
            conv_layer<32, 32>(xc, ec, c1_wq, c1_wk, c1_wv, c1_we, c1_weo,
                               qT, kT, vT, eT, en, xn, la, tid);

        // P5 (layers 0,1 only): x = leaky(LN(xn)), e = leaky(en)
        if (layer < 2) {
            const float* g  = (layer == 0) ? ln0_g : ln1_g;
            const float* be = (layer == 0) ? ln0_b : ln1_b;
            for (int idx = tid; idx < 288; idx += 512) {
                int j = idx >> 5, c = idx & 31;
                float mu = 0.f;
                #pragma unroll
                for (int t = 0; t < 32; ++t) mu += xn[j * 32 + t];
                mu *= (1.f / 32.f);
                float var = 0.f;
                #pragma unroll
                for (int t = 0; t < 32; ++t) { float d = xn[j * 32 + t] - mu; var = fmaf(d, d, var); }
                var *= (1.f / 32.f);
                float val = (xn[idx] - mu) / sqrtf(var + 1e-5f);
                val = val * g[c] + be[c];
                xc[idx] = (val > 0.f) ? val : 0.01f * val;
            }
            for (int idx = tid; idx < 2592; idx += 512) {
                float v = en[idx];
                ec[idx] = (v > 0.f) ? v : 0.01f * v;
            }
            __syncthreads();
        }
    }

    // Finals.  After layer 2 (no post): xn [9,32] raw, en [81,32] raw.
    float* out_x  = out;                       // [36864,10]
    float* out_e  = out + 368640;              // [294912,5]
    float* out_ei = out + 1843200;             // [2,294912]
    float* out_b  = out + 2433024;             // [36864]

    for (int idx = tid; idx < 90; idx += 512) {         // x @ w_feat
        int j = idx / 10, c = idx - j * 10;
        float acc = 0.f;
        #pragma unroll
        for (int kk = 0; kk < 32; ++kk) acc = fmaf(xn[j * 32 + kk], w_feat[kk * 10 + c], acc);
        out_x[(b * 9 + j) * 10 + c] = acc;
    }
    for (int idx = tid; idx < 360; idx += 512) {        // masked eattr @ w_eout
        int r = idx / 5, c = idx - r * 5;
        int i = r >> 3, jj = r & 7;
        int j = jj + (jj >= i ? 1 : 0);
        const float* row = &en[(i * 9 + j) * 32];
        float acc = 0.f;
        #pragma unroll
        for (int kk = 0; kk < 32; ++kk) acc = fmaf(row[kk], w_eout[kk * 5 + c], acc);
        out_e[(b * 72 + r) * 5 + c] = acc;
    }
    for (int idx = tid; idx < 72; idx += 512) {         // edge_index
        int i = idx >> 3, jj = idx & 7;
        int j = jj + (jj >= i ? 1 : 0);
        out_ei[b * 72 + idx]          = (float)(b * 9 + i);
        out_ei[294912 + b * 72 + idx] = (float)(b * 9 + j);
    }
    for (int idx = tid; idx < 9; idx += 512)            // batch
        out_b[b * 9 + idx] = (float)b;
}

// ---------------------------------------------------------------------------
extern "C" void kernel_launch(void* const* d_in, const int* in_sizes, int n_in,
                              void* d_out, int out_size, void* d_ws, size_t ws_size,
                              hipStream_t stream)
{
    const float* latent  = (const float*)d_in[0];
    const float* w_mlp0  = (const float*)d_in[1];
    const float* b_mlp0  = (const float*)d_in[2];
    const float* w_mlp1  = (const float*)d_in[3];
    const float* b_mlp1  = (const float*)d_in[4];
    const float* w_mlp2  = (const float*)d_in[5];
    const float* b_mlp2  = (const float*)d_in[6];
    const float* w_edges = (const float*)d_in[7];
    const float* b_edges = (const float*)d_in[8];
    const float* w_nodes = (const float*)d_in[9];
    const float* b_nodes = (const float*)d_in[10];
    const float* c0_wq   = (const float*)d_in[11];
    const float* c0_wk   = (const float*)d_in[12];
    const float* c0_wv   = (const float*)d_in[13];
    const float* c0_we   = (const float*)d_in[14];
    const float* c0_weo  = (const float*)d_in[15];
    const float* c1_wq   = (const float*)d_in[16];
    const float* c1_wk   = (const float*)d_in[17];
    const float* c1_wv   = (const float*)d_in[18];
    const float* c1_we   = (const float*)d_in[19];
    const float* c1_weo  = (const float*)d_in[20];
    const float* ln0_g   = (const float*)d_in[21];
    const float* ln0_b   = (const float*)d_in[22];
    const float* ln1_g   = (const float*)d_in[23];
    const float* ln1_b   = (const float*)d_in[24];
    const float* w_feat  = (const float*)d_in[25];
    const float* w_eout  = (const float*)d_in[26];

    // Workspace layout with lifetime overlap (peak 18.3 MB)
    float* ws = (float*)d_ws;
    float* h0 = ws;
    float* el = ws;
    float* h1 = ws + 1658880;
    float* nl = ws + 1658880;
    float* h2 = ws + 2707456;

    float* out = (float*)d_out;

    gemm_act_kernel<<<512, 256, 0, stream>>>(latent, w_mlp0, b_mlp0, h0, 128, 128, 1);
    gemm_act_kernel<<<512, 256, 0, stream>>>(h0, w_mlp1, b_mlp1, h1, 128, 256, 1);
    gemm_act_kernel<<<512, 256, 0, stream>>>(h1, w_mlp2, b_mlp2, h2, 256, 512, 1);
    gemm_act_kernel<<<512, 256, 0, stream>>>(h2, w_edges, b_edges, el, 512, 405, 0);
    gemm_act_kernel<<<512, 256, 0, stream>>>(h2, w_nodes, b_nodes, nl, 512, 117, 0);

    fused_gnn_kernel<<<B_, 512, 0, stream>>>(nl, el,
        c0_wq, c0_wk, c0_wv, c0_we, c0_weo,
        c1_wq, c1_wk, c1_wv, c1_we, c1_weo,
        ln0_g, ln0_b, ln1_g, ln1_b, w_feat, w_eout, out);
}

// Round 12
// 1252.946 us; speedup vs baseline: 5.1894x; 2.4973x over previous
//
#include <hip/hip_runtime.h>
#include <hip/hip_bf16.h>
#include <math.h>

#define B_    4096
#define V_    9
#define N_    (B_*V_)          // 36864 nodes
#define EK_   (B_*V_*(V_-1))   // 294912 kept edges

typedef unsigned short ushort_t;

__device__ __forceinline__ float b2f(ushort_t u) {
    union { unsigned int i; float f; } x; x.i = ((unsigned int)u) << 16; return x.f;
}
__device__ __forceinline__ ushort_t f2b(float f) {
    union { float f; unsigned int i; } x; x.f = f;
    unsigned int r = x.i + 0x7FFFu + ((x.i >> 16) & 1u);
    return (ushort_t)(r >> 16);
}

// ---------------------------------------------------------------------------
// Batched GEMM for the MLP head: out[M,Nc] = act(A[M,K] @ W[K,Nc] + bias)
// ---------------------------------------------------------------------------
__global__ __launch_bounds__(256) void gemm_act_kernel(
    const float* __restrict__ A, const float* __restrict__ W,
    const float* __restrict__ bias, float* __restrict__ out,
    int K, int Nc, int act)
{
    __shared__ float As[8 * 512];
    const int row0 = blockIdx.x * 8;
    const int tid  = threadIdx.x;

    for (int idx = tid; idx < 8 * K; idx += 256)
        As[idx] = A[row0 * K + idx];
    __syncthreads();

    const int total = 8 * Nc;
    for (int idx = tid; idx < total; idx += 256) {
        int r = idx / Nc;
        int n = idx - r * Nc;
        float acc = bias[n];
        const float* a = &As[r * K];
        for (int k = 0; k < K; ++k)
            acc = fmaf(a[k], W[k * Nc + n], acc);
        if (act == 1) acc = tanhf(acc);
        out[(row0 + r) * Nc + n] = acc;
    }
}

// ---------------------------------------------------------------------------
// One conv layer.  ALL weights read from LDS (bf16) -> inner loops are pure
// LDS traffic, minimal VGPR pressure (the r8/r10/r11 spill cause was in-flight
// GLOBAL weight loads).  Fragment layouts (ushort offsets) audited:
//   qT/kT/vT [32][36]: P1 write d-varying stride 18 words (2-way, free);
//     P2a/P3 reads consecutive-or-broadcast.
//   eT [32][324]: stride 162 words = 2 mod 32 -> 2-way, free.
//   weights [m][128]/[m][32] (global layout): lane-consecutive -> conflict-free.
// weo is staged into the DEAD qT/kT/vT region after P3 (3072 <= 3456 ush).
// ---------------------------------------------------------------------------
template <int XD, int ED2>
__device__ __forceinline__ void conv_layer(
    const float* __restrict__ xs,      // [9][XD] f32 LDS
    const ushort_t* __restrict__ es,   // [81][ED2] bf16 LDS
    const ushort_t* wqL, const ushort_t* wkL,
    const ushort_t* wvL, const ushort_t* weL,
    const float* __restrict__ weo_g,   // [2*XD+ED2][32] f32 global
    ushort_t* weoL,                    // aliases qT (dead after P3)
    ushort_t* qT, ushort_t* kT, ushort_t* vT, ushort_t* eT,
    float* en, float* xn, float* la, int tid)
{
    // P1: q,k,v projections (3*9*128) and e projection (81*128)
    for (int idx = tid; idx < 13824; idx += 512) {
        if (idx < 3456) {
            int which = idx / 1152, rem = idx - which * 1152;
            int node = rem >> 7, hd = rem & 127;
            int h = hd >> 5, d = hd & 31;
            const ushort_t* w = (which == 0) ? wqL : (which == 1) ? wkL : wvL;
            float acc = 0.f;
            #pragma unroll
            for (int m = 0; m < XD; ++m)
                acc = fmaf(xs[node * XD + m], b2f(w[m * 128 + hd]), acc);
            ushort_t* dst = (which == 0) ? qT : (which == 1) ? kT : vT;
            dst[d * 36 + node * 4 + h] = f2b(acc);
        } else {
            int r = idx - 3456;
            int le = r >> 7, hd = r & 127;
            int h = hd >> 5, d = hd & 31;
            float acc = 0.f;
            #pragma unroll
            for (int m = 0; m < ED2; ++m)
                acc = fmaf(b2f(es[le * ED2 + m]), b2f(weL[m * 128 + hd]), acc);
            eT[d * 324 + le * 4 + h] = f2b(acc);
        }
    }
    __syncthreads();

    // P2a: logits[le,h] = (q[dst=j] . (k[src=i]+e)) / sqrt(32)
    for (int idx = tid; idx < 324; idx += 512) {
        int le = idx >> 2, h = idx & 3;
        int i = le / 9, j = le - i * 9;
        float acc = 0.f;
        #pragma unroll
        for (int d = 0; d < 32; ++d)
            acc = fmaf(b2f(qT[d * 36 + j * 4 + h]),
                       b2f(kT[d * 36 + i * 4 + h]) + b2f(eT[d * 324 + le * 4 + h]), acc);
        la[idx] = acc * 0.17677669529663687f;
    }
    __syncthreads();

    // P2b: segment softmax over src i, per (dst j, head h), in place
    for (int s = tid; s < 36; s += 512) {
        int j = s >> 2, h = s & 3;
        float m = -1e30f;
        #pragma unroll
        for (int i = 0; i < 9; ++i) m = fmaxf(m, la[(i * 9 + j) * 4 + h]);
        float ex[9], sum = 0.f;
        #pragma unroll
        for (int i = 0; i < 9; ++i) { ex[i] = __expf(la[(i * 9 + j) * 4 + h] - m); sum += ex[i]; }
        float inv = 1.f / (sum + 1e-16f);
        #pragma unroll
        for (int i = 0; i < 9; ++i) la[(i * 9 + j) * 4 + h] = ex[i] * inv;
    }
    __syncthreads();

    // P3: aggregation -> xn[j,d] = mean_h sum_i alpha * (v[i]+e[le])
    for (int idx = tid; idx < 288; idx += 512) {
        int j = idx >> 5, d = idx & 31;
        float acc = 0.f;
        #pragma unroll
        for (int h = 0; h < 4; ++h)
            #pragma unroll
            for (int i = 0; i < 9; ++i) {
                int le = i * 9 + j;
                acc = fmaf(la[le * 4 + h],
                           b2f(vT[d * 36 + i * 4 + h]) + b2f(eT[d * 324 + le * 4 + h]), acc);
            }
        xn[idx] = acc * 0.25f;
    }
    __syncthreads();   // qT/kT/vT/eT reads done

    // stage weo (f32 global -> bf16 LDS) into the dead qkv region
    for (int idx = tid; idx < (2 * XD + ED2) * 32; idx += 512)
        weoL[idx] = f2b(weo_g[idx]);
    __syncthreads();

    // P4: edge out = concat(x[src], x[dst], e) @ weo -> en (aliases eT)
    for (int idx = tid; idx < 2592; idx += 512) {
        int le = idx >> 5, c = idx & 31;
        int i = le / 9, j = le - i * 9;
        float acc = 0.f;
        #pragma unroll
        for (int m = 0; m < XD;  ++m) acc = fmaf(xs[i * XD + m],        b2f(weoL[m * 32 + c]), acc);
        #pragma unroll
        for (int m = 0; m < XD;  ++m) acc = fmaf(xs[j * XD + m],        b2f(weoL[(XD + m) * 32 + c]), acc);
        #pragma unroll
        for (int m = 0; m < ED2; ++m) acc = fmaf(b2f(es[le * ED2 + m]), b2f(weoL[(2 * XD + m) * 32 + c]), acc);
        en[idx] = acc;
    }
    __syncthreads();   // xs/es reads done before caller overwrites xc/ec
}

// ---------------------------------------------------------------------------
// Fully fused GNN: 3 conv layers + finals.  One block (512 thr) per graph.
// LDS = 70480 B -> 70656 rounded = EXACTLY round-3's proven 2-blocks/CU size.
// All conv weights in bf16 LDS; spill ladder history:
//   cap 40: 14 GB scratch (r8) | cap 64: 3.9 GB (r10) | cap 128 + global
//   weights: 0.74 GB (r11).  LDS weights remove the ILP register need.
// ---------------------------------------------------------------------------
__global__ __launch_bounds__(512, 2) void fused_gnn_kernel(
    const float* __restrict__ nl,    // [B, 117]
    const float* __restrict__ el,    // [B, 405]
    const float* __restrict__ c0_wq, const float* __restrict__ c0_wk,
    const float* __restrict__ c0_wv, const float* __restrict__ c0_we,
    const float* __restrict__ c0_weo,
    const float* __restrict__ c1_wq, const float* __restrict__ c1_wk,
    const float* __restrict__ c1_wv, const float* __restrict__ c1_we,
    const float* __restrict__ c1_weo,
    const float* __restrict__ ln0_g, const float* __restrict__ ln0_b,
    const float* __restrict__ ln1_g, const float* __restrict__ ln1_b,
    const float* __restrict__ w_feat, const float* __restrict__ w_eout,
    float* __restrict__ out)
{
    __shared__ ushort_t smu[35240];          // 70480 B
    ushort_t* wqL = smu;                     // [<=32][128] bf16
    ushort_t* wkL = smu + 4096;
    ushort_t* wvL = smu + 8192;
    ushort_t* weL = smu + 12288;
    ushort_t* qT  = smu + 16384;             // [32][36]
    ushort_t* kT  = smu + 17536;
    ushort_t* vT  = smu + 18688;
    ushort_t* weoL= smu + 16384;             // alias qkv (3072 <= 3456)
    ushort_t* eT  = smu + 19840;             // [32][324]
    float*    en  = (float*)(smu + 19840);   // 2592 f32, aliases eT
    float*    xc  = (float*)(smu + 30208);   // [9][32] f32
    float*    xn  = (float*)(smu + 30784);   // [9][32] f32
    float*    la  = (float*)(smu + 31360);   // [81][4] f32
    ushort_t* ec  = smu + 32008;             // [81][32] bf16
    float*    x0s = (float*)(smu + 34600);   // [9][13] f32
    ushort_t* e0s = smu + 34834;             // [81][5] bf16

    const int b   = blockIdx.x;
    const int tid = threadIdx.x;

    // stage layer-0 inputs + c0 weights (bf16)
    for (int idx = tid; idx < 117; idx += 512) x0s[idx] = nl[b * 117 + idx];
    for (int idx = tid; idx < 405; idx += 512) {
        int le = idx / 5, c = idx - le * 5;
        int i = le / 9, j = le - i * 9;
        e0s[idx] = f2b(0.5f * (el[b * 405 + c * 81 + i * 9 + j] +
                               el[b * 405 + c * 81 + j * 9 + i]));
    }
    for (int idx = tid; idx < 13 * 128; idx += 512) {
        wqL[idx] = f2b(c0_wq[idx]);
        wkL[idx] = f2b(c0_wk[idx]);
        wvL[idx] = f2b(c0_wv[idx]);
    }
    for (int idx = tid; idx < 5 * 128; idx += 512) weL[idx] = f2b(c0_we[idx]);
    __syncthreads();

    for (int layer = 0; layer < 3; ++layer) {
        if (layer == 0)
            conv_layer<13, 5>(x0s, e0s, wqL, wkL, wvL, weL, c0_weo, weoL,
                              qT, kT, vT, eT, en, xn, la, tid);
        else
            conv_layer<32, 32>(xc, ec, wqL, wkL, wvL, weL, c1_weo, weoL,
                               qT, kT, vT, eT, en, xn, la, tid);

        // P5 (layers 0,1 only): x = leaky(LN(xn)), e = leaky(en)
        if (layer < 2) {
            const float* g  = (layer == 0) ? ln0_g : ln1_g;
            const float* be = (layer == 0) ? ln0_b : ln1_b;
            for (int idx = tid; idx < 288; idx += 512) {
                int j = idx >> 5, c = idx & 31;
                float mu = 0.f;
                #pragma unroll
                for (int t = 0; t < 32; ++t) mu += xn[j * 32 + t];
                mu *= (1.f / 32.f);
                float var = 0.f;
                #pragma unroll
                for (int t = 0; t < 32; ++t) { float d = xn[j * 32 + t] - mu; var = fmaf(d, d, var); }
                var *= (1.f / 32.f);
                float val = (xn[idx] - mu) / sqrtf(var + 1e-5f);
                val = val * g[c] + be[c];
                xc[idx] = (val > 0.f) ? val : 0.01f * val;
            }
            for (int idx = tid; idx < 2592; idx += 512) {
                float v = en[idx];
                ec[idx] = f2b((v > 0.f) ? v : 0.01f * v);
            }
            if (layer == 0) {   // restage weights: c0 -> c1 (layers 1 & 2)
                for (int idx = tid; idx < 32 * 128; idx += 512) {
                    wqL[idx] = f2b(c1_wq[idx]);
                    wkL[idx] = f2b(c1_wk[idx]);
                    wvL[idx] = f2b(c1_wv[idx]);
                    weL[idx] = f2b(c1_we[idx]);
                }
            }
            __syncthreads();
        }
    }

    // Finals.  After layer 2 (no post): xn [9,32] raw f32, en [81,32] raw f32.
    float* out_x  = out;                       // [36864,10]
    float* out_e  = out + 368640;              // [294912,5]
    float* out_ei = out + 1843200;             // [2,294912]
    float* out_b  = out + 2433024;             // [36864]

    for (int idx = tid; idx < 90; idx += 512) {         // x @ w_feat
        int j = idx / 10, c = idx - j * 10;
        float acc = 0.f;
        #pragma unroll
        for (int kk = 0; kk < 32; ++kk) acc = fmaf(xn[j * 32 + kk], w_feat[kk * 10 + c], acc);
        out_x[(b * 9 + j) * 10 + c] = acc;
    }
    for (int idx = tid; idx < 360; idx += 512) {        // masked eattr @ w_eout
        int r = idx / 5, c = idx - r * 5;
        int i = r >> 3, jj = r & 7;
        int j = jj + (jj >= i ? 1 : 0);
        const float* row = &en[(i * 9 + j) * 32];
        float acc = 0.f;
        #pragma unroll
        for (int kk = 0; kk < 32; ++kk) acc = fmaf(row[kk], w_eout[kk * 5 + c], acc);
        out_e[(b * 72 + r) * 5 + c] = acc;
    }
    for (int idx = tid; idx < 72; idx += 512) {         // edge_index
        int i = idx >> 3, jj = idx & 7;
        int j = jj + (jj >= i ? 1 : 0);
        out_ei[b * 72 + idx]          = (float)(b * 9 + i);
        out_ei[294912 + b * 72 + idx] = (float)(b * 9 + j);
    }
    for (int idx = tid; idx < 9; idx += 512)            // batch
        out_b[b * 9 + idx] = (float)b;
}

// ---------------------------------------------------------------------------
extern "C" void kernel_launch(void* const* d_in, const int* in_sizes, int n_in,
                              void* d_out, int out_size, void* d_ws, size_t ws_size,
                              hipStream_t stream)
{
    const float* latent  = (const float*)d_in[0];
    const float* w_mlp0  = (const float*)d_in[1];
    const float* b_mlp0  = (const float*)d_in[2];
    const float* w_mlp1  = (const float*)d_in[3];
    const float* b_mlp1  = (const float*)d_in[4];
    const float* w_mlp2  = (const float*)d_in[5];
    const float* b_mlp2  = (const float*)d_in[6];
    const float* w_edges = (const float*)d_in[7];
    const float* b_edges = (const float*)d_in[8];
    const float* w_nodes = (const float*)d_in[9];
    const float* b_nodes = (const float*)d_in[10];
    const float* c0_wq   = (const float*)d_in[11];
    const float* c0_wk   = (const float*)d_in[12];
    const float* c0_wv   = (const float*)d_in[13];
    const float* c0_we   = (const float*)d_in[14];
    const float* c0_weo  = (const float*)d_in[15];
    const float* c1_wq   = (const float*)d_in[16];
    const float* c1_wk   = (const float*)d_in[17];
    const float* c1_wv   = (const float*)d_in[18];
    const float* c1_we   = (const float*)d_in[19];
    const float* c1_weo  = (const float*)d_in[20];
    const float* ln0_g   = (const float*)d_in[21];
    const float* ln0_b   = (const float*)d_in[22];
    const float* ln1_g   = (const float*)d_in[23];
    const float* ln1_b   = (const float*)d_in[24];
    const float* w_feat  = (const float*)d_in[25];
    const float* w_eout  = (const float*)d_in[26];

    // Workspace layout with lifetime overlap (peak 18.3 MB)
    float* ws = (float*)d_ws;
    float* h0 = ws;
    float* el = ws;
    float* h1 = ws + 1658880;
    float* nl = ws + 1658880;
    float* h2 = ws + 2707456;

    float* out = (float*)d_out;

    gemm_act_kernel<<<512, 256, 0, stream>>>(latent, w_mlp0, b_mlp0, h0, 128, 128, 1);
    gemm_act_kernel<<<512, 256, 0, stream>>>(h0, w_mlp1, b_mlp1, h1, 128, 256, 1);
    gemm_act_kernel<<<512, 256, 0, stream>>>(h1, w_mlp2, b_mlp2, h2, 256, 512, 1);
    gemm_act_kernel<<<512, 256, 0, stream>>>(h2, w_edges, b_edges, el, 512, 405, 0);
    gemm_act_kernel<<<512, 256, 0, stream>>>(h2, w_nodes, b_nodes, nl, 512, 117, 0);

    fused_gnn_kernel<<<B_, 512, 0, stream>>>(nl, el,
        c0_wq, c0_wk, c0_wv, c0_we, c0_weo,
        c1_wq, c1_wk, c1_wv, c1_we, c1_weo,
        ln0_g, ln0_b, ln1_g, ln1_b, w_feat, w_eout, out);
}